// Round 8
// baseline (221.193 us; speedup 1.0000x reference)
//
#include <hip/hip_runtime.h>
#include <math.h>

#define N_NODES 1000
#define E_EDGES 64000
#define STRIDE  256   // padded CSR row stride (max degree ~110 for this graph)

typedef float fx4 __attribute__((ext_vector_type(4)));

__device__ inline float lrelu(float v){ return v > 0.f ? v : 0.1f * v; }

// ---- kA: CSR build (blocks 0..124, spin-synced) -> agg(x) -> GEMM1+tanh -> GEMM2
__global__ __launch_bounds__(1024)
void kA(const int* __restrict__ src, const int* __restrict__ dst,
        const float* __restrict__ x, int* __restrict__ cnt,
        int* __restrict__ csr, int* __restrict__ built,
        const float* __restrict__ W1, const float* __restrict__ b1,
        const float* __restrict__ W2, float* __restrict__ hs2){
  __shared__ float dinv_lds[1024];
  __shared__ fx4 gsum[4][8][32];     // gather partials (16 KB)
  __shared__ float xa[4 * 128];      // aggregated x rows
  __shared__ float h1s[4 * 512];     // tanh layer-1 output (8 KB)
  __shared__ fx4 red[7][4][128];     // k-slice reduce (56 KB)
  int b = blockIdx.x, t = threadIdx.x;
  // ---- CSR build: 125 producer blocks, 512 edges each ----
  if (b < 125){
    if (t < 512){
      int e = b * 512 + t;
      int s = src[e], d = dst[e];
      int pos = atomicAdd(&cnt[d], 1);
      if (pos < STRIDE) csr[(d << 8) + pos] = s;
    }
    __syncthreads();
    if (t == 0)
      __hip_atomic_fetch_add(built, 1, __ATOMIC_RELEASE, __HIP_MEMORY_SCOPE_AGENT);
  }
  // ---- spin until all producers signaled (producers self-satisfy: no deadlock) ----
  if (t == 0){
    while (__hip_atomic_load(built, __ATOMIC_ACQUIRE, __HIP_MEMORY_SCOPE_AGENT) < 125)
      __builtin_amdgcn_s_sleep(16);
  }
  __syncthreads();
  dinv_lds[t] = (t < N_NODES) ? rsqrtf((float)(cnt[t] + 1)) : 0.f;
  __syncthreads();
  // ---- gather x: node q, 256 thr/node: fx4 col c (32), slice sl (8) ----
  {
    int q = t >> 8, tt = t & 255;
    int c = tt & 31, sl = tt >> 5;
    int n = b * 4 + q;
    int m = cnt[n]; if (m > STRIDE) m = STRIDE;
    const fx4* x4 = (const fx4*)x;
    const int* row = csr + (n << 8);
    fx4 acc = {0.f, 0.f, 0.f, 0.f};
    if (sl == 0) acc = dinv_lds[n] * x4[n * 32 + c];   // self loop
    for (int i = sl; i < m; i += 8){
      int sv = row[i];
      acc += dinv_lds[sv] * x4[sv * 32 + c];
    }
    gsum[q][sl][c] = acc;
    __syncthreads();
    if (sl < 4) gsum[q][sl][c] += gsum[q][sl + 4][c];
    __syncthreads();
    if (sl < 2) gsum[q][sl][c] += gsum[q][sl + 2][c];
    __syncthreads();
    if (sl == 0)
      ((fx4*)xa)[q * 32 + c] = dinv_lds[n] * (gsum[q][0][c] + gsum[q][1][c]);
    __syncthreads();
  }
  int cq = t & 127, kh = t >> 7;
  // ---- GEMM1: [4x128]@[128x512] + b1, tanh -> h1s ----
  {
    fx4 a0 = {0,0,0,0}, a1 = {0,0,0,0}, a2 = {0,0,0,0}, a3 = {0,0,0,0};
    int kb = kh * 16;
    const fx4* Wp = (const fx4*)W1 + (size_t)kb * 128 + cq;
    #pragma unroll
    for (int k = 0; k < 16; ++k){
      fx4 w = Wp[k * 128];
      float h0 = xa[0 * 128 + kb + k], h1 = xa[1 * 128 + kb + k];
      float h2 = xa[2 * 128 + kb + k], h3 = xa[3 * 128 + kb + k];
      a0 += h0 * w; a1 += h1 * w; a2 += h2 * w; a3 += h3 * w;
    }
    if (kh > 0){
      red[kh-1][0][cq] = a0; red[kh-1][1][cq] = a1;
      red[kh-1][2][cq] = a2; red[kh-1][3][cq] = a3;
    }
    __syncthreads();
    if (kh == 0){
      #pragma unroll
      for (int s = 0; s < 7; ++s){
        a0 += red[s][0][cq]; a1 += red[s][1][cq];
        a2 += red[s][2][cq]; a3 += red[s][3][cq];
      }
      fx4 bb = ((const fx4*)b1)[cq];
      fx4* H = (fx4*)h1s;
      fx4 o;
      o.x=tanhf(a0.x+bb.x); o.y=tanhf(a0.y+bb.y); o.z=tanhf(a0.z+bb.z); o.w=tanhf(a0.w+bb.w); H[0*128+cq]=o;
      o.x=tanhf(a1.x+bb.x); o.y=tanhf(a1.y+bb.y); o.z=tanhf(a1.z+bb.z); o.w=tanhf(a1.w+bb.w); H[1*128+cq]=o;
      o.x=tanhf(a2.x+bb.x); o.y=tanhf(a2.y+bb.y); o.z=tanhf(a2.z+bb.z); o.w=tanhf(a2.w+bb.w); H[2*128+cq]=o;
      o.x=tanhf(a3.x+bb.x); o.y=tanhf(a3.y+bb.y); o.z=tanhf(a3.z+bb.z); o.w=tanhf(a3.w+bb.w); H[3*128+cq]=o;
    }
    __syncthreads();
  }
  // ---- GEMM2: [4x512]@[512x512] -> hs2 (pre-scaled by dinv_dst) ----
  {
    fx4 a0 = {0,0,0,0}, a1 = {0,0,0,0}, a2 = {0,0,0,0}, a3 = {0,0,0,0};
    int kb = kh * 64;
    const fx4* Wp = (const fx4*)W2 + (size_t)kb * 128 + cq;
    #pragma unroll 8
    for (int k = 0; k < 64; ++k){
      fx4 w = Wp[k * 128];
      float h0 = h1s[0 * 512 + kb + k], h1 = h1s[1 * 512 + kb + k];
      float h2 = h1s[2 * 512 + kb + k], h3 = h1s[3 * 512 + kb + k];
      a0 += h0 * w; a1 += h1 * w; a2 += h2 * w; a3 += h3 * w;
    }
    if (kh > 0){
      red[kh-1][0][cq] = a0; red[kh-1][1][cq] = a1;
      red[kh-1][2][cq] = a2; red[kh-1][3][cq] = a3;
    }
    __syncthreads();
    if (kh == 0){
      #pragma unroll
      for (int s = 0; s < 7; ++s){
        a0 += red[s][0][cq]; a1 += red[s][1][cq];
        a2 += red[s][2][cq]; a3 += red[s][3][cq];
      }
      int r0 = b * 4;
      fx4* O = (fx4*)hs2;
      O[(size_t)(r0 + 0) * 128 + cq] = a0 * dinv_lds[r0 + 0];
      O[(size_t)(r0 + 1) * 128 + cq] = a1 * dinv_lds[r0 + 1];
      O[(size_t)(r0 + 2) * 128 + cq] = a2 * dinv_lds[r0 + 2];
      O[(size_t)(r0 + 3) * 128 + cq] = a3 * dinv_lds[r0 + 3];
    }
  }
}

// ---- kB: agg(hs_in pre-scaled) + b,tanh -> register-tiled GEMM W3 -> hs_out pre-scaled
__global__ __launch_bounds__(1024)
void kB(const float* __restrict__ hs_in, const int* __restrict__ cnt,
        const int* __restrict__ csr, const float* __restrict__ bias,
        const float* __restrict__ W, float* __restrict__ hs_out){
  __shared__ float h2l[4 * 512];
  __shared__ fx4 hpart[4][128];
  __shared__ fx4 red[7][4][128];
  int b = blockIdx.x, t = threadIdx.x;
  {
    int q = t >> 8, tt = t & 255;
    int c = tt & 127, half = tt >> 7;
    int n = b * 4 + q;
    int m = cnt[n]; if (m > STRIDE) m = STRIDE;
    const fx4* h4 = (const fx4*)hs_in;
    const int* row = csr + (n << 8);
    fx4 s = {0.f, 0.f, 0.f, 0.f};
    if (half == 0) s = h4[n * 128 + c];            // self (pre-scaled)
    int i = half;
    for (; i + 6 < m; i += 8){
      int s0 = row[i], s1 = row[i + 2], s2 = row[i + 4], s3 = row[i + 6];
      s += h4[s0 * 128 + c] + h4[s1 * 128 + c]
         + h4[s2 * 128 + c] + h4[s3 * 128 + c];
    }
    for (; i < m; i += 2) s += h4[row[i] * 128 + c];
    if (half == 1) hpart[q][c] = s;
    __syncthreads();
    if (half == 0){
      s += hpart[q][c];
      float dn = rsqrtf((float)(m + 1));
      fx4 bb = ((const fx4*)bias)[c];
      fx4 o;
      o.x = tanhf(dn * s.x + bb.x);
      o.y = tanhf(dn * s.y + bb.y);
      o.z = tanhf(dn * s.z + bb.z);
      o.w = tanhf(dn * s.w + bb.w);
      ((fx4*)h2l)[q * 128 + c] = o;
    }
    __syncthreads();
  }
  // ---- GEMM: [4x512]@[512x512] register-tiled ----
  int cq = t & 127, kh = t >> 7;
  fx4 a0 = {0,0,0,0}, a1 = {0,0,0,0}, a2 = {0,0,0,0}, a3 = {0,0,0,0};
  int kb = kh * 64;
  const fx4* Wp = (const fx4*)W + (size_t)kb * 128 + cq;
  #pragma unroll 8
  for (int k = 0; k < 64; ++k){
    fx4 w = Wp[k * 128];
    float h0 = h2l[0 * 512 + kb + k], h1 = h2l[1 * 512 + kb + k];
    float h2 = h2l[2 * 512 + kb + k], h3 = h2l[3 * 512 + kb + k];
    a0 += h0 * w; a1 += h1 * w; a2 += h2 * w; a3 += h3 * w;
  }
  if (kh > 0){
    red[kh-1][0][cq] = a0; red[kh-1][1][cq] = a1;
    red[kh-1][2][cq] = a2; red[kh-1][3][cq] = a3;
  }
  __syncthreads();
  if (kh == 0){
    #pragma unroll
    for (int s = 0; s < 7; ++s){
      a0 += red[s][0][cq]; a1 += red[s][1][cq];
      a2 += red[s][2][cq]; a3 += red[s][3][cq];
    }
    int r0 = b * 4;
    fx4* O = (fx4*)hs_out;
    O[(size_t)(r0 + 0) * 128 + cq] = a0 * rsqrtf((float)(cnt[r0 + 0] + 1));
    O[(size_t)(r0 + 1) * 128 + cq] = a1 * rsqrtf((float)(cnt[r0 + 1] + 1));
    O[(size_t)(r0 + 2) * 128 + cq] = a2 * rsqrtf((float)(cnt[r0 + 2] + 1));
    O[(size_t)(r0 + 3) * 128 + cq] = a3 * rsqrtf((float)(cnt[r0 + 3] + 1));
  }
}

// ---- kC: Wd1 prefetch -> agg layer-3 -> NT-stream Wd1 -> partial; last block tail
__global__ __launch_bounds__(1024)
void kC(const float* __restrict__ hs_in, const int* __restrict__ cnt,
        const int* __restrict__ csr, const float* __restrict__ bias,
        const float* __restrict__ Wd1, float* __restrict__ partial,
        int* __restrict__ done,
        const float* __restrict__ bd1,
        const float* __restrict__ Wd2, const float* __restrict__ bd2,
        const float* __restrict__ Wd3, const float* __restrict__ bd3,
        const float* __restrict__ Wd4, const float* __restrict__ bd4,
        float* __restrict__ out){
  __shared__ float f_lds[2048];
  __shared__ fx4 red4[1024];
  __shared__ float y[256];
  __shared__ int flag;
  int b = blockIdx.x, t = threadIdx.x;
  // ---- issue Wd1 prefetch FIRST: loads depend on nothing; hide agg under HBM latency
  int r = t >> 6, c = t & 63;          // 16 rows in flight, 64 fx4 cols
  const fx4* W4 = (const fx4*)Wd1 + (size_t)b * 131072 + c;
  fx4 w_pre[8];
  #pragma unroll
  for (int j = 0; j < 8; ++j)
    w_pre[j] = __builtin_nontemporal_load(&W4[(size_t)(j * 16 + r) * 64]);
  // warm-touch Wd2/Wd3 into cache (evicted by the Wd1 stream each replay)
  if (b < 8){
    const fx4* w2 = (const fx4*)Wd2;
    const fx4* w3 = (const fx4*)Wd3;
    fx4 v0 = w2[b * 2048 + t] + w3[b * 2048 + t];
    fx4 v1 = w2[b * 2048 + 1024 + t] + w3[b * 2048 + 1024 + t];
    float dm = v0.x + v1.x;
    asm volatile("" :: "v"(dm));
  }
  // ---- agg (inputs pre-scaled by dinv[src]); 2-way edge slice, fx4 ----
  {
    int q = t >> 8, tt = t & 255;
    int cc = tt & 127, half = tt >> 7;
    int n = b * 4 + q;
    int m = cnt[n]; if (m > STRIDE) m = STRIDE;
    const fx4* h4 = (const fx4*)hs_in;
    const int* row = csr + (n << 8);
    fx4 s = {0.f, 0.f, 0.f, 0.f};
    if (half == 0) s = h4[n * 128 + cc];           // self (pre-scaled)
    int i = half;
    for (; i + 6 < m; i += 8){
      int s0 = row[i], s1 = row[i + 2], s2 = row[i + 4], s3 = row[i + 6];
      s += h4[s0 * 128 + cc] + h4[s1 * 128 + cc]
         + h4[s2 * 128 + cc] + h4[s3 * 128 + cc];
    }
    for (; i < m; i += 2) s += h4[row[i] * 128 + cc];
    if (half == 1) ((fx4*)red4)[q * 128 + cc] = s;  // reuse red4 as scratch
    __syncthreads();
    if (half == 0){
      s += ((fx4*)red4)[q * 128 + cc];
      float dn = rsqrtf((float)(m + 1));
      fx4 bb = ((const fx4*)bias)[cc];
      fx4 o;
      o.x = tanhf(dn * s.x + bb.x);
      o.y = tanhf(dn * s.y + bb.y);
      o.z = tanhf(dn * s.z + bb.z);
      o.w = tanhf(dn * s.w + bb.w);
      ((fx4*)f_lds)[q * 128 + cc] = o;
    }
    __syncthreads();
  }
  // ---- dense1: consume prefetch, then NT-stream the rest ----
  fx4 acc = {0.f, 0.f, 0.f, 0.f};
  #pragma unroll
  for (int j = 0; j < 8; ++j)
    acc += f_lds[j * 16 + r] * w_pre[j];
  #pragma unroll 8
  for (int it = 8; it < 128; ++it){
    int i2 = it * 16 + r;
    acc += f_lds[i2] * __builtin_nontemporal_load(&W4[(size_t)i2 * 64]);
  }
  red4[t] = acc;
  __syncthreads();
  if (t < 512) red4[t] += red4[t + 512];
  __syncthreads();
  if (t < 256) red4[t] += red4[t + 256];
  __syncthreads();
  if (t < 128) red4[t] += red4[t + 128];
  __syncthreads();
  if (t < 64) ((fx4*)(partial + b * 256))[t] = red4[t] + red4[t + 64];
  __syncthreads();
  // ---- last-block-done: only the final block runs the dense tail ----
  if (t == 0){
    __threadfence();
    int old = atomicAdd(done, 1);
    flag = (old == 249);
  }
  __syncthreads();
  if (!flag) return;
  __threadfence();
  float* sm = (float*)red4;
  int c2 = t & 255, h = t >> 8;
  // dense1 reduce + bias + lrelu
  float sum = 0.f;
  for (int bb2 = h; bb2 < 250; bb2 += 4) sum += partial[bb2 * 256 + c2];
  sm[t] = sum;
  __syncthreads();
  if (t < 512) sm[t] += sm[t + 512];
  __syncthreads();
  if (t < 256) y[t] = lrelu(sm[t] + sm[t + 256] + bd1[t]);
  __syncthreads();
  // dense2
  float a = 0.f;
  #pragma unroll 4
  for (int i3 = h * 64; i3 < h * 64 + 64; ++i3) a += y[i3] * Wd2[i3 * 256 + c2];
  sm[t] = a;
  __syncthreads();
  if (t < 512) sm[t] += sm[t + 512];
  __syncthreads();
  if (t < 256) y[t] = lrelu(sm[t] + sm[t + 256] + bd2[t]);
  __syncthreads();
  // dense3
  a = 0.f;
  #pragma unroll 4
  for (int i3 = h * 64; i3 < h * 64 + 64; ++i3) a += y[i3] * Wd3[i3 * 256 + c2];
  sm[t] = a;
  __syncthreads();
  if (t < 512) sm[t] += sm[t + 512];
  __syncthreads();
  if (t < 256) y[t] = lrelu(sm[t] + sm[t + 256] + bd3[t]);
  __syncthreads();
  // dense4
  sm[t] = (t < 256) ? y[t] * Wd4[t] : 0.f;
  __syncthreads();
  for (int off = 128; off > 0; off >>= 1){
    if (t < off) sm[t] += sm[t + off];
    __syncthreads();
  }
  if (t == 0) out[0] = sm[0] + bd4[0];
}

// ---------------- launch ----------------

extern "C" void kernel_launch(void* const* d_in, const int* in_sizes, int n_in,
                              void* d_out, int out_size, void* d_ws, size_t ws_size,
                              hipStream_t stream) {
  const float* x   = (const float*)d_in[0];
  const int*   ei  = (const int*)  d_in[1];
  const float* W1  = (const float*)d_in[2];  const float* b1  = (const float*)d_in[3];
  const float* W2  = (const float*)d_in[4];  const float* b2  = (const float*)d_in[5];
  const float* W3  = (const float*)d_in[6];  const float* b3  = (const float*)d_in[7];
  const float* Wd1 = (const float*)d_in[8];  const float* bd1 = (const float*)d_in[9];
  const float* Wd2 = (const float*)d_in[10]; const float* bd2 = (const float*)d_in[11];
  const float* Wd3 = (const float*)d_in[12]; const float* bd3 = (const float*)d_in[13];
  const float* Wd4 = (const float*)d_in[14]; const float* bd4 = (const float*)d_in[15];
  float* out = (float*)d_out;

  const int* src = ei;
  const int* dst = ei + E_EDGES;

  char* ws = (char*)d_ws;
  int*   cnt     = (int*)  (ws + 0);
  int*   done    = (int*)  (ws + 4096);
  int*   built   = (int*)  (ws + 4160);
  int*   csr     = (int*)  (ws + 8192);                   // 1000*256*4 B
  float* hsA     = (float*)(ws + 1114112);                // 2 MB
  float* hsB     = (float*)(ws + 1114112 + 2097152);      // 2 MB
  float* partial = (float*)(ws + 1114112 + 2 * 2097152);  // 250*256*4

  (void)hipMemsetAsync(ws, 0, 8192, stream);              // cnt + done + built
  kA<<<250, 1024, 0, stream>>>(src, dst, x, cnt, csr, built, W1, b1, W2, hsA);
  kB<<<250, 1024, 0, stream>>>(hsA, cnt, csr, b2, W3, hsB);
  kC<<<250, 1024, 0, stream>>>(hsB, cnt, csr, b3, Wd1, partial, done,
                               bd1, Wd2, bd2, Wd3, bd3, Wd4, bd4, out);
}

// Round 9
// 215.732 us; speedup vs baseline: 1.0253x; 1.0253x over previous
//
#include <hip/hip_runtime.h>
#include <math.h>

#define N_NODES 1000
#define E_EDGES 64000
#define STRIDE  256   // padded CSR row stride (max degree ~110 for this graph)

typedef float fx4 __attribute__((ext_vector_type(4)));

__device__ inline float lrelu(float v){ return v > 0.f ? v : 0.1f * v; }

// ---- kA: CSR build (blocks 0..124, spin-synced) -> agg(x) -> GEMM1+tanh -> GEMM2
__global__ __launch_bounds__(1024)
void kA(const int* __restrict__ src, const int* __restrict__ dst,
        const float* __restrict__ x, int* __restrict__ cnt,
        int* __restrict__ csr, int* __restrict__ built,
        const float* __restrict__ W1, const float* __restrict__ b1,
        const float* __restrict__ W2, float* __restrict__ hs2){
  __shared__ float dinv_lds[1024];
  __shared__ fx4 gsum[4][8][32];     // gather partials (16 KB)
  __shared__ float xa[4 * 128];      // aggregated x rows
  __shared__ float h1s[4 * 512];     // tanh layer-1 output (8 KB)
  __shared__ fx4 red[7][4][128];     // k-slice reduce (56 KB)
  int b = blockIdx.x, t = threadIdx.x;
  // ---- CSR build: 125 producer blocks, 512 edges each ----
  if (b < 125){
    if (t < 512){
      int e = b * 512 + t;
      int s = src[e], d = dst[e];
      int pos = atomicAdd(&cnt[d], 1);
      if (pos < STRIDE) csr[(d << 8) + pos] = s;
    }
    __syncthreads();
    if (t == 0)
      __hip_atomic_fetch_add(built, 1, __ATOMIC_RELEASE, __HIP_MEMORY_SCOPE_AGENT);
  }
  // ---- spin until all producers signaled (producers self-satisfy: no deadlock) ----
  if (t == 0){
    while (__hip_atomic_load(built, __ATOMIC_ACQUIRE, __HIP_MEMORY_SCOPE_AGENT) < 125)
      __builtin_amdgcn_s_sleep(16);
  }
  __syncthreads();
  dinv_lds[t] = (t < N_NODES) ? rsqrtf((float)(cnt[t] + 1)) : 0.f;
  __syncthreads();
  // ---- gather x: node q, 256 thr/node: fx4 col c (32), slice sl (8) ----
  {
    int q = t >> 8, tt = t & 255;
    int c = tt & 31, sl = tt >> 5;
    int n = b * 4 + q;
    int m = cnt[n]; if (m > STRIDE) m = STRIDE;
    const fx4* x4 = (const fx4*)x;
    const int* row = csr + (n << 8);
    fx4 acc = {0.f, 0.f, 0.f, 0.f};
    if (sl == 0) acc = dinv_lds[n] * x4[n * 32 + c];   // self loop
    for (int i = sl; i < m; i += 8){
      int sv = row[i];
      acc += dinv_lds[sv] * x4[sv * 32 + c];
    }
    gsum[q][sl][c] = acc;
    __syncthreads();
    if (sl < 4) gsum[q][sl][c] += gsum[q][sl + 4][c];
    __syncthreads();
    if (sl < 2) gsum[q][sl][c] += gsum[q][sl + 2][c];
    __syncthreads();
    if (sl == 0)
      ((fx4*)xa)[q * 32 + c] = dinv_lds[n] * (gsum[q][0][c] + gsum[q][1][c]);
    __syncthreads();
  }
  int cq = t & 127, kh = t >> 7;
  // ---- GEMM1: [4x128]@[128x512] + b1, tanh -> h1s ----
  {
    fx4 a0 = {0,0,0,0}, a1 = {0,0,0,0}, a2 = {0,0,0,0}, a3 = {0,0,0,0};
    int kb = kh * 16;
    const fx4* Wp = (const fx4*)W1 + (size_t)kb * 128 + cq;
    #pragma unroll
    for (int k = 0; k < 16; ++k){
      fx4 w = Wp[k * 128];
      float h0 = xa[0 * 128 + kb + k], h1 = xa[1 * 128 + kb + k];
      float h2 = xa[2 * 128 + kb + k], h3 = xa[3 * 128 + kb + k];
      a0 += h0 * w; a1 += h1 * w; a2 += h2 * w; a3 += h3 * w;
    }
    if (kh > 0){
      red[kh-1][0][cq] = a0; red[kh-1][1][cq] = a1;
      red[kh-1][2][cq] = a2; red[kh-1][3][cq] = a3;
    }
    __syncthreads();
    if (kh == 0){
      #pragma unroll
      for (int s = 0; s < 7; ++s){
        a0 += red[s][0][cq]; a1 += red[s][1][cq];
        a2 += red[s][2][cq]; a3 += red[s][3][cq];
      }
      fx4 bb = ((const fx4*)b1)[cq];
      fx4* H = (fx4*)h1s;
      fx4 o;
      o.x=tanhf(a0.x+bb.x); o.y=tanhf(a0.y+bb.y); o.z=tanhf(a0.z+bb.z); o.w=tanhf(a0.w+bb.w); H[0*128+cq]=o;
      o.x=tanhf(a1.x+bb.x); o.y=tanhf(a1.y+bb.y); o.z=tanhf(a1.z+bb.z); o.w=tanhf(a1.w+bb.w); H[1*128+cq]=o;
      o.x=tanhf(a2.x+bb.x); o.y=tanhf(a2.y+bb.y); o.z=tanhf(a2.z+bb.z); o.w=tanhf(a2.w+bb.w); H[2*128+cq]=o;
      o.x=tanhf(a3.x+bb.x); o.y=tanhf(a3.y+bb.y); o.z=tanhf(a3.z+bb.z); o.w=tanhf(a3.w+bb.w); H[3*128+cq]=o;
    }
    __syncthreads();
  }
  // ---- GEMM2: [4x512]@[512x512] -> hs2 (pre-scaled by dinv_dst) ----
  {
    fx4 a0 = {0,0,0,0}, a1 = {0,0,0,0}, a2 = {0,0,0,0}, a3 = {0,0,0,0};
    int kb = kh * 64;
    const fx4* Wp = (const fx4*)W2 + (size_t)kb * 128 + cq;
    #pragma unroll 8
    for (int k = 0; k < 64; ++k){
      fx4 w = Wp[k * 128];
      float h0 = h1s[0 * 512 + kb + k], h1 = h1s[1 * 512 + kb + k];
      float h2 = h1s[2 * 512 + kb + k], h3 = h1s[3 * 512 + kb + k];
      a0 += h0 * w; a1 += h1 * w; a2 += h2 * w; a3 += h3 * w;
    }
    if (kh > 0){
      red[kh-1][0][cq] = a0; red[kh-1][1][cq] = a1;
      red[kh-1][2][cq] = a2; red[kh-1][3][cq] = a3;
    }
    __syncthreads();
    if (kh == 0){
      #pragma unroll
      for (int s = 0; s < 7; ++s){
        a0 += red[s][0][cq]; a1 += red[s][1][cq];
        a2 += red[s][2][cq]; a3 += red[s][3][cq];
      }
      int r0 = b * 4;
      fx4* O = (fx4*)hs2;
      O[(size_t)(r0 + 0) * 128 + cq] = a0 * dinv_lds[r0 + 0];
      O[(size_t)(r0 + 1) * 128 + cq] = a1 * dinv_lds[r0 + 1];
      O[(size_t)(r0 + 2) * 128 + cq] = a2 * dinv_lds[r0 + 2];
      O[(size_t)(r0 + 3) * 128 + cq] = a3 * dinv_lds[r0 + 3];
    }
  }
}

// ---- kB: agg(hs_in pre-scaled) + b,tanh -> register-tiled GEMM W3 -> hs_out pre-scaled
__global__ __launch_bounds__(1024)
void kB(const float* __restrict__ hs_in, const int* __restrict__ cnt,
        const int* __restrict__ csr, const float* __restrict__ bias,
        const float* __restrict__ W, float* __restrict__ hs_out){
  __shared__ float h2l[4 * 512];
  __shared__ fx4 hpart[4][128];
  __shared__ fx4 red[7][4][128];
  int b = blockIdx.x, t = threadIdx.x;
  {
    int q = t >> 8, tt = t & 255;
    int c = tt & 127, half = tt >> 7;
    int n = b * 4 + q;
    int m = cnt[n]; if (m > STRIDE) m = STRIDE;
    const fx4* h4 = (const fx4*)hs_in;
    const int* row = csr + (n << 8);
    fx4 s = {0.f, 0.f, 0.f, 0.f};
    if (half == 0) s = h4[n * 128 + c];            // self (pre-scaled)
    int i = half;
    for (; i + 6 < m; i += 8){
      int s0 = row[i], s1 = row[i + 2], s2 = row[i + 4], s3 = row[i + 6];
      s += h4[s0 * 128 + c] + h4[s1 * 128 + c]
         + h4[s2 * 128 + c] + h4[s3 * 128 + c];
    }
    for (; i < m; i += 2) s += h4[row[i] * 128 + c];
    if (half == 1) hpart[q][c] = s;
    __syncthreads();
    if (half == 0){
      s += hpart[q][c];
      float dn = rsqrtf((float)(m + 1));
      fx4 bb = ((const fx4*)bias)[c];
      fx4 o;
      o.x = tanhf(dn * s.x + bb.x);
      o.y = tanhf(dn * s.y + bb.y);
      o.z = tanhf(dn * s.z + bb.z);
      o.w = tanhf(dn * s.w + bb.w);
      ((fx4*)h2l)[q * 128 + c] = o;
    }
    __syncthreads();
  }
  // ---- GEMM: [4x512]@[512x512] register-tiled ----
  int cq = t & 127, kh = t >> 7;
  fx4 a0 = {0,0,0,0}, a1 = {0,0,0,0}, a2 = {0,0,0,0}, a3 = {0,0,0,0};
  int kb = kh * 64;
  const fx4* Wp = (const fx4*)W + (size_t)kb * 128 + cq;
  #pragma unroll 8
  for (int k = 0; k < 64; ++k){
    fx4 w = Wp[k * 128];
    float h0 = h2l[0 * 512 + kb + k], h1 = h2l[1 * 512 + kb + k];
    float h2 = h2l[2 * 512 + kb + k], h3 = h2l[3 * 512 + kb + k];
    a0 += h0 * w; a1 += h1 * w; a2 += h2 * w; a3 += h3 * w;
  }
  if (kh > 0){
    red[kh-1][0][cq] = a0; red[kh-1][1][cq] = a1;
    red[kh-1][2][cq] = a2; red[kh-1][3][cq] = a3;
  }
  __syncthreads();
  if (kh == 0){
    #pragma unroll
    for (int s = 0; s < 7; ++s){
      a0 += red[s][0][cq]; a1 += red[s][1][cq];
      a2 += red[s][2][cq]; a3 += red[s][3][cq];
    }
    int r0 = b * 4;
    fx4* O = (fx4*)hs_out;
    O[(size_t)(r0 + 0) * 128 + cq] = a0 * rsqrtf((float)(cnt[r0 + 0] + 1));
    O[(size_t)(r0 + 1) * 128 + cq] = a1 * rsqrtf((float)(cnt[r0 + 1] + 1));
    O[(size_t)(r0 + 2) * 128 + cq] = a2 * rsqrtf((float)(cnt[r0 + 2] + 1));
    O[(size_t)(r0 + 3) * 128 + cq] = a3 * rsqrtf((float)(cnt[r0 + 3] + 1));
  }
}

// ---- kC: agg layer-3 -> f_lds -> NT-stream Wd1 -> partial; last block tail
__global__ __launch_bounds__(1024)
void kC(const float* __restrict__ hs_in, const int* __restrict__ cnt,
        const int* __restrict__ csr, const float* __restrict__ bias,
        const float* __restrict__ Wd1, float* __restrict__ partial,
        int* __restrict__ done,
        const float* __restrict__ bd1,
        const float* __restrict__ Wd2, const float* __restrict__ bd2,
        const float* __restrict__ Wd3, const float* __restrict__ bd3,
        const float* __restrict__ Wd4, const float* __restrict__ bd4,
        float* __restrict__ out){
  __shared__ float f_lds[2048];
  __shared__ fx4 red4[1024];
  __shared__ float y[256];
  __shared__ int flag;
  int b = blockIdx.x, t = threadIdx.x;
  // warm-touch Wd2/Wd3 into cache (evicted by the Wd1 stream each replay)
  if (b < 8){
    const fx4* w2 = (const fx4*)Wd2;
    const fx4* w3 = (const fx4*)Wd3;
    fx4 v0 = w2[b * 2048 + t] + w3[b * 2048 + t];
    fx4 v1 = w2[b * 2048 + 1024 + t] + w3[b * 2048 + 1024 + t];
    float dm = v0.x + v1.x;
    asm volatile("" :: "v"(dm));
  }
  // ---- agg (inputs pre-scaled by dinv[src]); 2-way edge slice, fx4 ----
  {
    int q = t >> 8, tt = t & 255;
    int cc = tt & 127, half = tt >> 7;
    int n = b * 4 + q;
    int m = cnt[n]; if (m > STRIDE) m = STRIDE;
    const fx4* h4 = (const fx4*)hs_in;
    const int* row = csr + (n << 8);
    fx4 s = {0.f, 0.f, 0.f, 0.f};
    if (half == 0) s = h4[n * 128 + cc];           // self (pre-scaled)
    int i = half;
    for (; i + 6 < m; i += 8){
      int s0 = row[i], s1 = row[i + 2], s2 = row[i + 4], s3 = row[i + 6];
      s += h4[s0 * 128 + cc] + h4[s1 * 128 + cc]
         + h4[s2 * 128 + cc] + h4[s3 * 128 + cc];
    }
    for (; i < m; i += 2) s += h4[row[i] * 128 + cc];
    if (half == 1) ((fx4*)red4)[q * 128 + cc] = s;  // reuse red4 as scratch
    __syncthreads();
    if (half == 0){
      s += ((fx4*)red4)[q * 128 + cc];
      float dn = rsqrtf((float)(m + 1));
      fx4 bb = ((const fx4*)bias)[cc];
      fx4 o;
      o.x = tanhf(dn * s.x + bb.x);
      o.y = tanhf(dn * s.y + bb.y);
      o.z = tanhf(dn * s.z + bb.z);
      o.w = tanhf(dn * s.w + bb.w);
      ((fx4*)f_lds)[q * 128 + cc] = o;
    }
    __syncthreads();
  }
  // ---- dense1: NT-stream 2048 rows x 256 cols of Wd1 ----
  int r = t >> 6, c = t & 63;          // 16 rows in flight, 64 fx4 cols
  const fx4* W4 = (const fx4*)Wd1 + (size_t)b * 131072 + c;
  fx4 acc = {0.f, 0.f, 0.f, 0.f};
  #pragma unroll 8
  for (int it = 0; it < 128; ++it){
    int i2 = it * 16 + r;
    acc += f_lds[i2] * __builtin_nontemporal_load(&W4[(size_t)i2 * 64]);
  }
  red4[t] = acc;
  __syncthreads();
  if (t < 512) red4[t] += red4[t + 512];
  __syncthreads();
  if (t < 256) red4[t] += red4[t + 256];
  __syncthreads();
  if (t < 128) red4[t] += red4[t + 128];
  __syncthreads();
  if (t < 64) ((fx4*)(partial + b * 256))[t] = red4[t] + red4[t + 64];
  __syncthreads();
  // ---- last-block-done: only the final block runs the dense tail ----
  if (t == 0){
    __threadfence();
    int old = atomicAdd(done, 1);
    flag = (old == 249);
  }
  __syncthreads();
  if (!flag) return;
  __threadfence();
  float* sm = (float*)red4;
  int c2 = t & 255, h = t >> 8;
  // dense1 reduce + bias + lrelu
  float sum = 0.f;
  for (int bb2 = h; bb2 < 250; bb2 += 4) sum += partial[bb2 * 256 + c2];
  sm[t] = sum;
  __syncthreads();
  if (t < 512) sm[t] += sm[t + 512];
  __syncthreads();
  if (t < 256) y[t] = lrelu(sm[t] + sm[t + 256] + bd1[t]);
  __syncthreads();
  // dense2
  float a = 0.f;
  #pragma unroll 4
  for (int i3 = h * 64; i3 < h * 64 + 64; ++i3) a += y[i3] * Wd2[i3 * 256 + c2];
  sm[t] = a;
  __syncthreads();
  if (t < 512) sm[t] += sm[t + 512];
  __syncthreads();
  if (t < 256) y[t] = lrelu(sm[t] + sm[t + 256] + bd2[t]);
  __syncthreads();
  // dense3
  a = 0.f;
  #pragma unroll 4
  for (int i3 = h * 64; i3 < h * 64 + 64; ++i3) a += y[i3] * Wd3[i3 * 256 + c2];
  sm[t] = a;
  __syncthreads();
  if (t < 512) sm[t] += sm[t + 512];
  __syncthreads();
  if (t < 256) y[t] = lrelu(sm[t] + sm[t + 256] + bd3[t]);
  __syncthreads();
  // dense4
  sm[t] = (t < 256) ? y[t] * Wd4[t] : 0.f;
  __syncthreads();
  for (int off = 128; off > 0; off >>= 1){
    if (t < off) sm[t] += sm[t + off];
    __syncthreads();
  }
  if (t == 0) out[0] = sm[0] + bd4[0];
}

// ---------------- launch ----------------

extern "C" void kernel_launch(void* const* d_in, const int* in_sizes, int n_in,
                              void* d_out, int out_size, void* d_ws, size_t ws_size,
                              hipStream_t stream) {
  const float* x   = (const float*)d_in[0];
  const int*   ei  = (const int*)  d_in[1];
  const float* W1  = (const float*)d_in[2];  const float* b1  = (const float*)d_in[3];
  const float* W2  = (const float*)d_in[4];  const float* b2  = (const float*)d_in[5];
  const float* W3  = (const float*)d_in[6];  const float* b3  = (const float*)d_in[7];
  const float* Wd1 = (const float*)d_in[8];  const float* bd1 = (const float*)d_in[9];
  const float* Wd2 = (const float*)d_in[10]; const float* bd2 = (const float*)d_in[11];
  const float* Wd3 = (const float*)d_in[12]; const float* bd3 = (const float*)d_in[13];
  const float* Wd4 = (const float*)d_in[14]; const float* bd4 = (const float*)d_in[15];
  float* out = (float*)d_out;

  const int* src = ei;
  const int* dst = ei + E_EDGES;

  char* ws = (char*)d_ws;
  int*   cnt     = (int*)  (ws + 0);
  int*   done    = (int*)  (ws + 4096);
  int*   built   = (int*)  (ws + 4160);
  int*   csr     = (int*)  (ws + 8192);                   // 1000*256*4 B
  float* hsA     = (float*)(ws + 1114112);                // 2 MB
  float* hsB     = (float*)(ws + 1114112 + 2097152);      // 2 MB
  float* partial = (float*)(ws + 1114112 + 2 * 2097152);  // 250*256*4

  (void)hipMemsetAsync(ws, 0, 8192, stream);              // cnt + done + built
  kA<<<250, 1024, 0, stream>>>(src, dst, x, cnt, csr, built, W1, b1, W2, hsA);
  kB<<<250, 1024, 0, stream>>>(hsA, cnt, csr, b2, W3, hsB);
  kC<<<250, 1024, 0, stream>>>(hsB, cnt, csr, b3, Wd1, partial, done,
                               bd1, Wd2, bd2, Wd3, bd3, Wd4, bd4, out);
}

// Round 10
// 195.769 us; speedup vs baseline: 1.1299x; 1.1020x over previous
//
#include <hip/hip_runtime.h>
#include <math.h>

#define N_NODES 1000
#define E_EDGES 64000
#define STRIDE  256   // padded CSR row stride (max degree ~110 for this graph)

typedef float fx4 __attribute__((ext_vector_type(4)));

__device__ inline float lrelu(float v){ return v > 0.f ? v : 0.1f * v; }

// ---- k0: padded-CSR build only
__global__ __launch_bounds__(512)
void k0(const int* __restrict__ src, const int* __restrict__ dst,
        int* __restrict__ cnt, int* __restrict__ csr){
  int e = blockIdx.x * 512 + threadIdx.x;       // 125*512 == 64000 exactly
  int s = src[e], d = dst[e];
  int pos = atomicAdd(&cnt[d], 1);
  if (pos < STRIDE) csr[(d << 8) + pos] = s;
}

// ---- kA: agg(x) [128-wide] -> GEMM1+b1+tanh -> GEMM2 -> hs2 = dinv (.) (h1@W2)
__global__ __launch_bounds__(1024)
void kA(const float* __restrict__ x, const int* __restrict__ cnt,
        const int* __restrict__ csr, const float* __restrict__ W1,
        const float* __restrict__ b1, const float* __restrict__ W2,
        float* __restrict__ hs2){
  __shared__ float dinv_lds[1024];
  __shared__ fx4 gsum[4][8][32];     // gather partials (16 KB)
  __shared__ float xa[4 * 128];      // aggregated x rows
  __shared__ float h1s[4 * 512];     // tanh layer-1 output (8 KB)
  __shared__ fx4 red[7][4][128];     // k-slice reduce (56 KB)
  int b = blockIdx.x, t = threadIdx.x;
  dinv_lds[t] = (t < N_NODES) ? rsqrtf((float)(cnt[t] + 1)) : 0.f;
  __syncthreads();
  // ---- gather x: node q, 256 thr/node: fx4 col c (32), slice sl (8) ----
  {
    int q = t >> 8, tt = t & 255;
    int c = tt & 31, sl = tt >> 5;
    int n = b * 4 + q;
    int m = cnt[n]; if (m > STRIDE) m = STRIDE;
    const fx4* x4 = (const fx4*)x;
    const int* row = csr + (n << 8);
    fx4 acc = {0.f, 0.f, 0.f, 0.f};
    if (sl == 0) acc = dinv_lds[n] * x4[n * 32 + c];   // self loop
    for (int i = sl; i < m; i += 8){
      int sv = row[i];
      acc += dinv_lds[sv] * x4[sv * 32 + c];
    }
    gsum[q][sl][c] = acc;
    __syncthreads();
    if (sl < 4) gsum[q][sl][c] += gsum[q][sl + 4][c];
    __syncthreads();
    if (sl < 2) gsum[q][sl][c] += gsum[q][sl + 2][c];
    __syncthreads();
    if (sl == 0)
      ((fx4*)xa)[q * 32 + c] = dinv_lds[n] * (gsum[q][0][c] + gsum[q][1][c]);
    __syncthreads();
  }
  int cq = t & 127, kh = t >> 7;
  // ---- GEMM1: [4x128]@[128x512] + b1, tanh -> h1s ----
  {
    fx4 a0 = {0,0,0,0}, a1 = {0,0,0,0}, a2 = {0,0,0,0}, a3 = {0,0,0,0};
    int kb = kh * 16;
    const fx4* Wp = (const fx4*)W1 + (size_t)kb * 128 + cq;
    #pragma unroll
    for (int k = 0; k < 16; ++k){
      fx4 w = Wp[k * 128];
      float h0 = xa[0 * 128 + kb + k], h1 = xa[1 * 128 + kb + k];
      float h2 = xa[2 * 128 + kb + k], h3 = xa[3 * 128 + kb + k];
      a0 += h0 * w; a1 += h1 * w; a2 += h2 * w; a3 += h3 * w;
    }
    if (kh > 0){
      red[kh-1][0][cq] = a0; red[kh-1][1][cq] = a1;
      red[kh-1][2][cq] = a2; red[kh-1][3][cq] = a3;
    }
    __syncthreads();
    if (kh == 0){
      #pragma unroll
      for (int s = 0; s < 7; ++s){
        a0 += red[s][0][cq]; a1 += red[s][1][cq];
        a2 += red[s][2][cq]; a3 += red[s][3][cq];
      }
      fx4 bb = ((const fx4*)b1)[cq];
      fx4* H = (fx4*)h1s;
      fx4 o;
      o.x=tanhf(a0.x+bb.x); o.y=tanhf(a0.y+bb.y); o.z=tanhf(a0.z+bb.z); o.w=tanhf(a0.w+bb.w); H[0*128+cq]=o;
      o.x=tanhf(a1.x+bb.x); o.y=tanhf(a1.y+bb.y); o.z=tanhf(a1.z+bb.z); o.w=tanhf(a1.w+bb.w); H[1*128+cq]=o;
      o.x=tanhf(a2.x+bb.x); o.y=tanhf(a2.y+bb.y); o.z=tanhf(a2.z+bb.z); o.w=tanhf(a2.w+bb.w); H[2*128+cq]=o;
      o.x=tanhf(a3.x+bb.x); o.y=tanhf(a3.y+bb.y); o.z=tanhf(a3.z+bb.z); o.w=tanhf(a3.w+bb.w); H[3*128+cq]=o;
    }
    __syncthreads();
  }
  // ---- GEMM2: [4x512]@[512x512] -> hs2 (pre-scaled by dinv_dst) ----
  {
    fx4 a0 = {0,0,0,0}, a1 = {0,0,0,0}, a2 = {0,0,0,0}, a3 = {0,0,0,0};
    int kb = kh * 64;
    const fx4* Wp = (const fx4*)W2 + (size_t)kb * 128 + cq;
    #pragma unroll 8
    for (int k = 0; k < 64; ++k){
      fx4 w = Wp[k * 128];
      float h0 = h1s[0 * 512 + kb + k], h1 = h1s[1 * 512 + kb + k];
      float h2 = h1s[2 * 512 + kb + k], h3 = h1s[3 * 512 + kb + k];
      a0 += h0 * w; a1 += h1 * w; a2 += h2 * w; a3 += h3 * w;
    }
    if (kh > 0){
      red[kh-1][0][cq] = a0; red[kh-1][1][cq] = a1;
      red[kh-1][2][cq] = a2; red[kh-1][3][cq] = a3;
    }
    __syncthreads();
    if (kh == 0){
      #pragma unroll
      for (int s = 0; s < 7; ++s){
        a0 += red[s][0][cq]; a1 += red[s][1][cq];
        a2 += red[s][2][cq]; a3 += red[s][3][cq];
      }
      int r0 = b * 4;
      fx4* O = (fx4*)hs2;
      O[(size_t)(r0 + 0) * 128 + cq] = a0 * dinv_lds[r0 + 0];
      O[(size_t)(r0 + 1) * 128 + cq] = a1 * dinv_lds[r0 + 1];
      O[(size_t)(r0 + 2) * 128 + cq] = a2 * dinv_lds[r0 + 2];
      O[(size_t)(r0 + 3) * 128 + cq] = a3 * dinv_lds[r0 + 3];
    }
  }
}

// ---- kB: agg(hs_in pre-scaled) + b,tanh -> register-tiled GEMM W3 -> hs_out pre-scaled
__global__ __launch_bounds__(1024)
void kB(const float* __restrict__ hs_in, const int* __restrict__ cnt,
        const int* __restrict__ csr, const float* __restrict__ bias,
        const float* __restrict__ W, float* __restrict__ hs_out){
  __shared__ float h2l[4 * 512];
  __shared__ fx4 hpart[4][128];
  __shared__ fx4 red[7][4][128];
  int b = blockIdx.x, t = threadIdx.x;
  {
    int q = t >> 8, tt = t & 255;
    int c = tt & 127, half = tt >> 7;
    int n = b * 4 + q;
    int m = cnt[n]; if (m > STRIDE) m = STRIDE;
    const fx4* h4 = (const fx4*)hs_in;
    const int* row = csr + (n << 8);
    fx4 s = {0.f, 0.f, 0.f, 0.f};
    if (half == 0) s = h4[n * 128 + c];            // self (pre-scaled)
    int i = half;
    for (; i + 6 < m; i += 8){
      int s0 = row[i], s1 = row[i + 2], s2 = row[i + 4], s3 = row[i + 6];
      s += h4[s0 * 128 + c] + h4[s1 * 128 + c]
         + h4[s2 * 128 + c] + h4[s3 * 128 + c];
    }
    for (; i < m; i += 2) s += h4[row[i] * 128 + c];
    if (half == 1) hpart[q][c] = s;
    __syncthreads();
    if (half == 0){
      s += hpart[q][c];
      float dn = rsqrtf((float)(m + 1));
      fx4 bb = ((const fx4*)bias)[c];
      fx4 o;
      o.x = tanhf(dn * s.x + bb.x);
      o.y = tanhf(dn * s.y + bb.y);
      o.z = tanhf(dn * s.z + bb.z);
      o.w = tanhf(dn * s.w + bb.w);
      ((fx4*)h2l)[q * 128 + c] = o;
    }
    __syncthreads();
  }
  // ---- GEMM: [4x512]@[512x512] register-tiled ----
  int cq = t & 127, kh = t >> 7;
  fx4 a0 = {0,0,0,0}, a1 = {0,0,0,0}, a2 = {0,0,0,0}, a3 = {0,0,0,0};
  int kb = kh * 64;
  const fx4* Wp = (const fx4*)W + (size_t)kb * 128 + cq;
  #pragma unroll 8
  for (int k = 0; k < 64; ++k){
    fx4 w = Wp[k * 128];
    float h0 = h2l[0 * 512 + kb + k], h1 = h2l[1 * 512 + kb + k];
    float h2 = h2l[2 * 512 + kb + k], h3 = h2l[3 * 512 + kb + k];
    a0 += h0 * w; a1 += h1 * w; a2 += h2 * w; a3 += h3 * w;
  }
  if (kh > 0){
    red[kh-1][0][cq] = a0; red[kh-1][1][cq] = a1;
    red[kh-1][2][cq] = a2; red[kh-1][3][cq] = a3;
  }
  __syncthreads();
  if (kh == 0){
    #pragma unroll
    for (int s = 0; s < 7; ++s){
      a0 += red[s][0][cq]; a1 += red[s][1][cq];
      a2 += red[s][2][cq]; a3 += red[s][3][cq];
    }
    int r0 = b * 4;
    fx4* O = (fx4*)hs_out;
    O[(size_t)(r0 + 0) * 128 + cq] = a0 * rsqrtf((float)(cnt[r0 + 0] + 1));
    O[(size_t)(r0 + 1) * 128 + cq] = a1 * rsqrtf((float)(cnt[r0 + 1] + 1));
    O[(size_t)(r0 + 2) * 128 + cq] = a2 * rsqrtf((float)(cnt[r0 + 2] + 1));
    O[(size_t)(r0 + 3) * 128 + cq] = a3 * rsqrtf((float)(cnt[r0 + 3] + 1));
  }
}

// ---- kC: agg layer-3 -> f_lds -> NT-stream Wd1 -> partial; last block tail
__global__ __launch_bounds__(1024)
void kC(const float* __restrict__ hs_in, const int* __restrict__ cnt,
        const int* __restrict__ csr, const float* __restrict__ bias,
        const float* __restrict__ Wd1, float* __restrict__ partial,
        int* __restrict__ done,
        const float* __restrict__ bd1,
        const float* __restrict__ Wd2, const float* __restrict__ bd2,
        const float* __restrict__ Wd3, const float* __restrict__ bd3,
        const float* __restrict__ Wd4, const float* __restrict__ bd4,
        float* __restrict__ out){
  __shared__ float f_lds[2048];
  __shared__ fx4 red4[1024];
  __shared__ float y[256];
  __shared__ int flag;
  int b = blockIdx.x, t = threadIdx.x;
  // warm-touch Wd2/Wd3 into cache (evicted by the Wd1 stream each replay)
  if (b < 8){
    const fx4* w2 = (const fx4*)Wd2;
    const fx4* w3 = (const fx4*)Wd3;
    fx4 v0 = w2[b * 2048 + t] + w3[b * 2048 + t];
    fx4 v1 = w2[b * 2048 + 1024 + t] + w3[b * 2048 + 1024 + t];
    float dm = v0.x + v1.x;
    asm volatile("" :: "v"(dm));
  }
  // ---- agg (inputs pre-scaled by dinv[src]); 2-way edge slice, fx4 ----
  {
    int q = t >> 8, tt = t & 255;
    int cc = tt & 127, half = tt >> 7;
    int n = b * 4 + q;
    int m = cnt[n]; if (m > STRIDE) m = STRIDE;
    const fx4* h4 = (const fx4*)hs_in;
    const int* row = csr + (n << 8);
    fx4 s = {0.f, 0.f, 0.f, 0.f};
    if (half == 0) s = h4[n * 128 + cc];           // self (pre-scaled)
    int i = half;
    for (; i + 6 < m; i += 8){
      int s0 = row[i], s1 = row[i + 2], s2 = row[i + 4], s3 = row[i + 6];
      s += h4[s0 * 128 + cc] + h4[s1 * 128 + cc]
         + h4[s2 * 128 + cc] + h4[s3 * 128 + cc];
    }
    for (; i < m; i += 2) s += h4[row[i] * 128 + cc];
    if (half == 1) ((fx4*)red4)[q * 128 + cc] = s;  // reuse red4 as scratch
    __syncthreads();
    if (half == 0){
      s += ((fx4*)red4)[q * 128 + cc];
      float dn = rsqrtf((float)(m + 1));
      fx4 bb = ((const fx4*)bias)[cc];
      fx4 o;
      o.x = tanhf(dn * s.x + bb.x);
      o.y = tanhf(dn * s.y + bb.y);
      o.z = tanhf(dn * s.z + bb.z);
      o.w = tanhf(dn * s.w + bb.w);
      ((fx4*)f_lds)[q * 128 + cc] = o;
    }
    __syncthreads();
  }
  // ---- dense1: NT-stream 2048 rows x 256 cols of Wd1 ----
  int r = t >> 6, c = t & 63;          // 16 rows in flight, 64 fx4 cols
  const fx4* W4 = (const fx4*)Wd1 + (size_t)b * 131072 + c;
  fx4 acc = {0.f, 0.f, 0.f, 0.f};
  #pragma unroll 8
  for (int it = 0; it < 128; ++it){
    int i2 = it * 16 + r;
    acc += f_lds[i2] * __builtin_nontemporal_load(&W4[(size_t)i2 * 64]);
  }
  red4[t] = acc;
  __syncthreads();
  if (t < 512) red4[t] += red4[t + 512];
  __syncthreads();
  if (t < 256) red4[t] += red4[t + 256];
  __syncthreads();
  if (t < 128) red4[t] += red4[t + 128];
  __syncthreads();
  if (t < 64) ((fx4*)(partial + b * 256))[t] = red4[t] + red4[t + 64];
  __syncthreads();
  // ---- last-block-done: only the final block runs the dense tail ----
  if (t == 0){
    __threadfence();
    int old = atomicAdd(done, 1);
    flag = (old == 249);
  }
  __syncthreads();
  if (!flag) return;
  __threadfence();
  float* sm = (float*)red4;
  int c2 = t & 255, h = t >> 8;
  // dense1 reduce + bias + lrelu
  float sum = 0.f;
  for (int bb2 = h; bb2 < 250; bb2 += 4) sum += partial[bb2 * 256 + c2];
  sm[t] = sum;
  __syncthreads();
  if (t < 512) sm[t] += sm[t + 512];
  __syncthreads();
  if (t < 256) y[t] = lrelu(sm[t] + sm[t + 256] + bd1[t]);
  __syncthreads();
  // dense2
  float a = 0.f;
  #pragma unroll 4
  for (int i3 = h * 64; i3 < h * 64 + 64; ++i3) a += y[i3] * Wd2[i3 * 256 + c2];
  sm[t] = a;
  __syncthreads();
  if (t < 512) sm[t] += sm[t + 512];
  __syncthreads();
  if (t < 256) y[t] = lrelu(sm[t] + sm[t + 256] + bd2[t]);
  __syncthreads();
  // dense3
  a = 0.f;
  #pragma unroll 4
  for (int i3 = h * 64; i3 < h * 64 + 64; ++i3) a += y[i3] * Wd3[i3 * 256 + c2];
  sm[t] = a;
  __syncthreads();
  if (t < 512) sm[t] += sm[t + 512];
  __syncthreads();
  if (t < 256) y[t] = lrelu(sm[t] + sm[t + 256] + bd3[t]);
  __syncthreads();
  // dense4
  sm[t] = (t < 256) ? y[t] * Wd4[t] : 0.f;
  __syncthreads();
  for (int off = 128; off > 0; off >>= 1){
    if (t < off) sm[t] += sm[t + off];
    __syncthreads();
  }
  if (t == 0) out[0] = sm[0] + bd4[0];
}

// ---------------- launch ----------------

extern "C" void kernel_launch(void* const* d_in, const int* in_sizes, int n_in,
                              void* d_out, int out_size, void* d_ws, size_t ws_size,
                              hipStream_t stream) {
  const float* x   = (const float*)d_in[0];
  const int*   ei  = (const int*)  d_in[1];
  const float* W1  = (const float*)d_in[2];  const float* b1  = (const float*)d_in[3];
  const float* W2  = (const float*)d_in[4];  const float* b2  = (const float*)d_in[5];
  const float* W3  = (const float*)d_in[6];  const float* b3  = (const float*)d_in[7];
  const float* Wd1 = (const float*)d_in[8];  const float* bd1 = (const float*)d_in[9];
  const float* Wd2 = (const float*)d_in[10]; const float* bd2 = (const float*)d_in[11];
  const float* Wd3 = (const float*)d_in[12]; const float* bd3 = (const float*)d_in[13];
  const float* Wd4 = (const float*)d_in[14]; const float* bd4 = (const float*)d_in[15];
  float* out = (float*)d_out;

  const int* src = ei;
  const int* dst = ei + E_EDGES;

  char* ws = (char*)d_ws;
  int*   cnt     = (int*)  (ws + 0);
  int*   done    = (int*)  (ws + 4096);
  int*   csr     = (int*)  (ws + 8192);                   // 1000*256*4 B
  float* hsA     = (float*)(ws + 1114112);                // 2 MB
  float* hsB     = (float*)(ws + 1114112 + 2097152);      // 2 MB
  float* partial = (float*)(ws + 1114112 + 2 * 2097152);  // 250*256*4

  (void)hipMemsetAsync(ws, 0, 8192, stream);              // cnt + done
  k0<<<125, 512, 0, stream>>>(src, dst, cnt, csr);
  kA<<<250, 1024, 0, stream>>>(x, cnt, csr, W1, b1, W2, hsA);
  kB<<<250, 1024, 0, stream>>>(hsA, cnt, csr, b2, W3, hsB);
  kC<<<250, 1024, 0, stream>>>(hsB, cnt, csr, b3, Wd1, partial, done,
                               bd1, Wd2, bd2, Wd3, bd3, Wd4, bd4, out);
}

// Round 11
// 179.467 us; speedup vs baseline: 1.2325x; 1.0908x over previous
//
#include <hip/hip_runtime.h>
#include <math.h>

#define N_NODES 1000
#define E_EDGES 64000
#define STRIDE  256   // padded CSR row stride (max degree ~110 for this graph)

typedef float fx4 __attribute__((ext_vector_type(4)));

__device__ inline float lrelu(float v){ return v > 0.f ? v : 0.1f * v; }

// ---- kA: per-block edge scan (hist -> dinv; own CSR rows) -> agg(x) -> GEMM1+tanh -> GEMM2
// Writes cnt + own csr rows for kB/kC; zeroes `done` for kC. No memset / k0 needed.
__global__ __launch_bounds__(1024)
void kA(const int* __restrict__ src, const int* __restrict__ dst,
        const float* __restrict__ x, int* __restrict__ cnt,
        int* __restrict__ csr, int* __restrict__ done,
        const float* __restrict__ W1, const float* __restrict__ b1,
        const float* __restrict__ W2, float* __restrict__ hs2){
  __shared__ int   hist[1024];
  __shared__ int   own_cnt[4];
  __shared__ int   own_src[4][STRIDE];
  __shared__ float dinv_lds[1024];
  __shared__ fx4   gsum[4][8][32];   // gather partials (16 KB)
  __shared__ float xa[4 * 128];      // aggregated x rows
  __shared__ float h1s[4 * 512];     // tanh layer-1 output (8 KB)
  __shared__ fx4   red[7][4][128];   // k-slice reduce (56 KB)
  int b = blockIdx.x, t = threadIdx.x;

  // ---- phase 0: edge scan ----
  hist[t] = 0;
  if (t < 4) own_cnt[t] = 0;
  if (t == 0 && b == 0) *done = 0;
  __syncthreads();
  {
    const int4* s4p = (const int4*)src;
    const int4* d4p = (const int4*)dst;
    for (int i = t; i < E_EDGES / 4; i += 1024){
      int4 d4 = d4p[i];
      int4 s4 = s4p[i];
      #pragma unroll
      for (int j = 0; j < 4; ++j){
        int d = (j == 0) ? d4.x : (j == 1) ? d4.y : (j == 2) ? d4.z : d4.w;
        int s = (j == 0) ? s4.x : (j == 1) ? s4.y : (j == 2) ? s4.z : s4.w;
        atomicAdd(&hist[d], 1);
        if ((d >> 2) == b){
          int pos = atomicAdd(&own_cnt[d & 3], 1);
          if (pos < STRIDE) own_src[d & 3][pos] = s;
        }
      }
    }
  }
  __syncthreads();
  dinv_lds[t] = (t < N_NODES) ? rsqrtf((float)(hist[t] + 1)) : 0.f;
  // publish cnt + own csr rows for kB/kC (disjoint writes, no atomics)
  if (t < 4) cnt[b * 4 + t] = own_cnt[t];
  for (int i = t; i < 4 * STRIDE; i += 1024){
    int q = i >> 8, pos = i & 255;
    if (pos < own_cnt[q]) csr[((b * 4 + q) << 8) + pos] = own_src[q][pos];
  }
  __syncthreads();

  // ---- gather x: node q, 256 thr/node: fx4 col c (32), slice sl (8) ----
  {
    int q = t >> 8, tt = t & 255;
    int c = tt & 31, sl = tt >> 5;
    int n = b * 4 + q;
    int m = own_cnt[q]; if (m > STRIDE) m = STRIDE;
    const fx4* x4 = (const fx4*)x;
    fx4 acc = {0.f, 0.f, 0.f, 0.f};
    if (sl == 0) acc = dinv_lds[n] * x4[n * 32 + c];   // self loop
    for (int i = sl; i < m; i += 8){
      int sv = own_src[q][i];
      acc += dinv_lds[sv] * x4[sv * 32 + c];
    }
    gsum[q][sl][c] = acc;
    __syncthreads();
    if (sl < 4) gsum[q][sl][c] += gsum[q][sl + 4][c];
    __syncthreads();
    if (sl < 2) gsum[q][sl][c] += gsum[q][sl + 2][c];
    __syncthreads();
    if (sl == 0)
      ((fx4*)xa)[q * 32 + c] = dinv_lds[n] * (gsum[q][0][c] + gsum[q][1][c]);
    __syncthreads();
  }
  int cq = t & 127, kh = t >> 7;
  // ---- GEMM1: [4x128]@[128x512] + b1, tanh -> h1s ----
  {
    fx4 a0 = {0,0,0,0}, a1 = {0,0,0,0}, a2 = {0,0,0,0}, a3 = {0,0,0,0};
    int kb = kh * 16;
    const fx4* Wp = (const fx4*)W1 + (size_t)kb * 128 + cq;
    #pragma unroll
    for (int k = 0; k < 16; ++k){
      fx4 w = Wp[k * 128];
      float h0 = xa[0 * 128 + kb + k], h1 = xa[1 * 128 + kb + k];
      float h2 = xa[2 * 128 + kb + k], h3 = xa[3 * 128 + kb + k];
      a0 += h0 * w; a1 += h1 * w; a2 += h2 * w; a3 += h3 * w;
    }
    if (kh > 0){
      red[kh-1][0][cq] = a0; red[kh-1][1][cq] = a1;
      red[kh-1][2][cq] = a2; red[kh-1][3][cq] = a3;
    }
    __syncthreads();
    if (kh == 0){
      #pragma unroll
      for (int s = 0; s < 7; ++s){
        a0 += red[s][0][cq]; a1 += red[s][1][cq];
        a2 += red[s][2][cq]; a3 += red[s][3][cq];
      }
      fx4 bb = ((const fx4*)b1)[cq];
      fx4* H = (fx4*)h1s;
      fx4 o;
      o.x=tanhf(a0.x+bb.x); o.y=tanhf(a0.y+bb.y); o.z=tanhf(a0.z+bb.z); o.w=tanhf(a0.w+bb.w); H[0*128+cq]=o;
      o.x=tanhf(a1.x+bb.x); o.y=tanhf(a1.y+bb.y); o.z=tanhf(a1.z+bb.z); o.w=tanhf(a1.w+bb.w); H[1*128+cq]=o;
      o.x=tanhf(a2.x+bb.x); o.y=tanhf(a2.y+bb.y); o.z=tanhf(a2.z+bb.z); o.w=tanhf(a2.w+bb.w); H[2*128+cq]=o;
      o.x=tanhf(a3.x+bb.x); o.y=tanhf(a3.y+bb.y); o.z=tanhf(a3.z+bb.z); o.w=tanhf(a3.w+bb.w); H[3*128+cq]=o;
    }
    __syncthreads();
  }
  // ---- GEMM2: [4x512]@[512x512] -> hs2 (pre-scaled by dinv_dst) ----
  {
    fx4 a0 = {0,0,0,0}, a1 = {0,0,0,0}, a2 = {0,0,0,0}, a3 = {0,0,0,0};
    int kb = kh * 64;
    const fx4* Wp = (const fx4*)W2 + (size_t)kb * 128 + cq;
    #pragma unroll 8
    for (int k = 0; k < 64; ++k){
      fx4 w = Wp[k * 128];
      float h0 = h1s[0 * 512 + kb + k], h1 = h1s[1 * 512 + kb + k];
      float h2 = h1s[2 * 512 + kb + k], h3 = h1s[3 * 512 + kb + k];
      a0 += h0 * w; a1 += h1 * w; a2 += h2 * w; a3 += h3 * w;
    }
    if (kh > 0){
      red[kh-1][0][cq] = a0; red[kh-1][1][cq] = a1;
      red[kh-1][2][cq] = a2; red[kh-1][3][cq] = a3;
    }
    __syncthreads();
    if (kh == 0){
      #pragma unroll
      for (int s = 0; s < 7; ++s){
        a0 += red[s][0][cq]; a1 += red[s][1][cq];
        a2 += red[s][2][cq]; a3 += red[s][3][cq];
      }
      int r0 = b * 4;
      fx4* O = (fx4*)hs2;
      O[(size_t)(r0 + 0) * 128 + cq] = a0 * dinv_lds[r0 + 0];
      O[(size_t)(r0 + 1) * 128 + cq] = a1 * dinv_lds[r0 + 1];
      O[(size_t)(r0 + 2) * 128 + cq] = a2 * dinv_lds[r0 + 2];
      O[(size_t)(r0 + 3) * 128 + cq] = a3 * dinv_lds[r0 + 3];
    }
  }
}

// ---- kB: agg(hs_in pre-scaled) + b,tanh -> register-tiled GEMM W3 -> hs_out pre-scaled
__global__ __launch_bounds__(1024)
void kB(const float* __restrict__ hs_in, const int* __restrict__ cnt,
        const int* __restrict__ csr, const float* __restrict__ bias,
        const float* __restrict__ W, float* __restrict__ hs_out){
  __shared__ float h2l[4 * 512];
  __shared__ fx4 hpart[4][128];
  __shared__ fx4 red[7][4][128];
  int b = blockIdx.x, t = threadIdx.x;
  {
    int q = t >> 8, tt = t & 255;
    int c = tt & 127, half = tt >> 7;
    int n = b * 4 + q;
    int m = cnt[n]; if (m > STRIDE) m = STRIDE;
    const fx4* h4 = (const fx4*)hs_in;
    const int* row = csr + (n << 8);
    fx4 s = {0.f, 0.f, 0.f, 0.f};
    if (half == 0) s = h4[n * 128 + c];            // self (pre-scaled)
    int i = half;
    for (; i + 6 < m; i += 8){
      int s0 = row[i], s1 = row[i + 2], s2 = row[i + 4], s3 = row[i + 6];
      s += h4[s0 * 128 + c] + h4[s1 * 128 + c]
         + h4[s2 * 128 + c] + h4[s3 * 128 + c];
    }
    for (; i < m; i += 2) s += h4[row[i] * 128 + c];
    if (half == 1) hpart[q][c] = s;
    __syncthreads();
    if (half == 0){
      s += hpart[q][c];
      float dn = rsqrtf((float)(m + 1));
      fx4 bb = ((const fx4*)bias)[c];
      fx4 o;
      o.x = tanhf(dn * s.x + bb.x);
      o.y = tanhf(dn * s.y + bb.y);
      o.z = tanhf(dn * s.z + bb.z);
      o.w = tanhf(dn * s.w + bb.w);
      ((fx4*)h2l)[q * 128 + c] = o;
    }
    __syncthreads();
  }
  // ---- GEMM: [4x512]@[512x512] register-tiled ----
  int cq = t & 127, kh = t >> 7;
  fx4 a0 = {0,0,0,0}, a1 = {0,0,0,0}, a2 = {0,0,0,0}, a3 = {0,0,0,0};
  int kb = kh * 64;
  const fx4* Wp = (const fx4*)W + (size_t)kb * 128 + cq;
  #pragma unroll 8
  for (int k = 0; k < 64; ++k){
    fx4 w = Wp[k * 128];
    float h0 = h2l[0 * 512 + kb + k], h1 = h2l[1 * 512 + kb + k];
    float h2 = h2l[2 * 512 + kb + k], h3 = h2l[3 * 512 + kb + k];
    a0 += h0 * w; a1 += h1 * w; a2 += h2 * w; a3 += h3 * w;
  }
  if (kh > 0){
    red[kh-1][0][cq] = a0; red[kh-1][1][cq] = a1;
    red[kh-1][2][cq] = a2; red[kh-1][3][cq] = a3;
  }
  __syncthreads();
  if (kh == 0){
    #pragma unroll
    for (int s = 0; s < 7; ++s){
      a0 += red[s][0][cq]; a1 += red[s][1][cq];
      a2 += red[s][2][cq]; a3 += red[s][3][cq];
    }
    int r0 = b * 4;
    fx4* O = (fx4*)hs_out;
    O[(size_t)(r0 + 0) * 128 + cq] = a0 * rsqrtf((float)(cnt[r0 + 0] + 1));
    O[(size_t)(r0 + 1) * 128 + cq] = a1 * rsqrtf((float)(cnt[r0 + 1] + 1));
    O[(size_t)(r0 + 2) * 128 + cq] = a2 * rsqrtf((float)(cnt[r0 + 2] + 1));
    O[(size_t)(r0 + 3) * 128 + cq] = a3 * rsqrtf((float)(cnt[r0 + 3] + 1));
  }
}

// ---- kC: agg layer-3 -> f_lds -> NT-stream Wd1 -> partial; last block tail
__global__ __launch_bounds__(1024)
void kC(const float* __restrict__ hs_in, const int* __restrict__ cnt,
        const int* __restrict__ csr, const float* __restrict__ bias,
        const float* __restrict__ Wd1, float* __restrict__ partial,
        int* __restrict__ done,
        const float* __restrict__ bd1,
        const float* __restrict__ Wd2, const float* __restrict__ bd2,
        const float* __restrict__ Wd3, const float* __restrict__ bd3,
        const float* __restrict__ Wd4, const float* __restrict__ bd4,
        float* __restrict__ out){
  __shared__ float f_lds[2048];
  __shared__ fx4 red4[1024];
  __shared__ float y[256];
  __shared__ int flag;
  int b = blockIdx.x, t = threadIdx.x;
  // warm-touch Wd2/Wd3 into cache (evicted by the Wd1 stream each replay)
  if (b < 8){
    const fx4* w2 = (const fx4*)Wd2;
    const fx4* w3 = (const fx4*)Wd3;
    fx4 v0 = w2[b * 2048 + t] + w3[b * 2048 + t];
    fx4 v1 = w2[b * 2048 + 1024 + t] + w3[b * 2048 + 1024 + t];
    float dm = v0.x + v1.x;
    asm volatile("" :: "v"(dm));
  }
  // ---- agg (inputs pre-scaled by dinv[src]); 2-way edge slice, fx4 ----
  {
    int q = t >> 8, tt = t & 255;
    int cc = tt & 127, half = tt >> 7;
    int n = b * 4 + q;
    int m = cnt[n]; if (m > STRIDE) m = STRIDE;
    const fx4* h4 = (const fx4*)hs_in;
    const int* row = csr + (n << 8);
    fx4 s = {0.f, 0.f, 0.f, 0.f};
    if (half == 0) s = h4[n * 128 + cc];           // self (pre-scaled)
    int i = half;
    for (; i + 6 < m; i += 8){
      int s0 = row[i], s1 = row[i + 2], s2 = row[i + 4], s3 = row[i + 6];
      s += h4[s0 * 128 + cc] + h4[s1 * 128 + cc]
         + h4[s2 * 128 + cc] + h4[s3 * 128 + cc];
    }
    for (; i < m; i += 2) s += h4[row[i] * 128 + cc];
    if (half == 1) ((fx4*)red4)[q * 128 + cc] = s;  // reuse red4 as scratch
    __syncthreads();
    if (half == 0){
      s += ((fx4*)red4)[q * 128 + cc];
      float dn = rsqrtf((float)(m + 1));
      fx4 bb = ((const fx4*)bias)[cc];
      fx4 o;
      o.x = tanhf(dn * s.x + bb.x);
      o.y = tanhf(dn * s.y + bb.y);
      o.z = tanhf(dn * s.z + bb.z);
      o.w = tanhf(dn * s.w + bb.w);
      ((fx4*)f_lds)[q * 128 + cc] = o;
    }
    __syncthreads();
  }
  // ---- dense1: NT-stream 2048 rows x 256 cols of Wd1 ----
  int r = t >> 6, c = t & 63;          // 16 rows in flight, 64 fx4 cols
  const fx4* W4 = (const fx4*)Wd1 + (size_t)b * 131072 + c;
  fx4 acc = {0.f, 0.f, 0.f, 0.f};
  #pragma unroll 8
  for (int it = 0; it < 128; ++it){
    int i2 = it * 16 + r;
    acc += f_lds[i2] * __builtin_nontemporal_load(&W4[(size_t)i2 * 64]);
  }
  red4[t] = acc;
  __syncthreads();
  if (t < 512) red4[t] += red4[t + 512];
  __syncthreads();
  if (t < 256) red4[t] += red4[t + 256];
  __syncthreads();
  if (t < 128) red4[t] += red4[t + 128];
  __syncthreads();
  if (t < 64) ((fx4*)(partial + b * 256))[t] = red4[t] + red4[t + 64];
  __syncthreads();
  // ---- last-block-done: only the final block runs the dense tail ----
  if (t == 0){
    __threadfence();
    int old = atomicAdd(done, 1);
    flag = (old == 249);
  }
  __syncthreads();
  if (!flag) return;
  __threadfence();
  float* sm = (float*)red4;
  int c2 = t & 255, h = t >> 8;
  // dense1 reduce + bias + lrelu
  float sum = 0.f;
  for (int bb2 = h; bb2 < 250; bb2 += 4) sum += partial[bb2 * 256 + c2];
  sm[t] = sum;
  __syncthreads();
  if (t < 512) sm[t] += sm[t + 512];
  __syncthreads();
  if (t < 256) y[t] = lrelu(sm[t] + sm[t + 256] + bd1[t]);
  __syncthreads();
  // dense2
  float a = 0.f;
  #pragma unroll 4
  for (int i3 = h * 64; i3 < h * 64 + 64; ++i3) a += y[i3] * Wd2[i3 * 256 + c2];
  sm[t] = a;
  __syncthreads();
  if (t < 512) sm[t] += sm[t + 512];
  __syncthreads();
  if (t < 256) y[t] = lrelu(sm[t] + sm[t + 256] + bd2[t]);
  __syncthreads();
  // dense3
  a = 0.f;
  #pragma unroll 4
  for (int i3 = h * 64; i3 < h * 64 + 64; ++i3) a += y[i3] * Wd3[i3 * 256 + c2];
  sm[t] = a;
  __syncthreads();
  if (t < 512) sm[t] += sm[t + 512];
  __syncthreads();
  if (t < 256) y[t] = lrelu(sm[t] + sm[t + 256] + bd3[t]);
  __syncthreads();
  // dense4
  sm[t] = (t < 256) ? y[t] * Wd4[t] : 0.f;
  __syncthreads();
  for (int off = 128; off > 0; off >>= 1){
    if (t < off) sm[t] += sm[t + off];
    __syncthreads();
  }
  if (t == 0) out[0] = sm[0] + bd4[0];
}

// ---------------- launch ----------------

extern "C" void kernel_launch(void* const* d_in, const int* in_sizes, int n_in,
                              void* d_out, int out_size, void* d_ws, size_t ws_size,
                              hipStream_t stream) {
  const float* x   = (const float*)d_in[0];
  const int*   ei  = (const int*)  d_in[1];
  const float* W1  = (const float*)d_in[2];  const float* b1  = (const float*)d_in[3];
  const float* W2  = (const float*)d_in[4];  const float* b2  = (const float*)d_in[5];
  const float* W3  = (const float*)d_in[6];  const float* b3  = (const float*)d_in[7];
  const float* Wd1 = (const float*)d_in[8];  const float* bd1 = (const float*)d_in[9];
  const float* Wd2 = (const float*)d_in[10]; const float* bd2 = (const float*)d_in[11];
  const float* Wd3 = (const float*)d_in[12]; const float* bd3 = (const float*)d_in[13];
  const float* Wd4 = (const float*)d_in[14]; const float* bd4 = (const float*)d_in[15];
  float* out = (float*)d_out;

  const int* src = ei;
  const int* dst = ei + E_EDGES;

  char* ws = (char*)d_ws;
  int*   cnt     = (int*)  (ws + 0);
  int*   done    = (int*)  (ws + 4096);
  int*   csr     = (int*)  (ws + 8192);                   // 1000*256*4 B
  float* hsA     = (float*)(ws + 1114112);                // 2 MB
  float* hsB     = (float*)(ws + 1114112 + 2097152);      // 2 MB
  float* partial = (float*)(ws + 1114112 + 2 * 2097152);  // 250*256*4

  kA<<<250, 1024, 0, stream>>>(src, dst, x, cnt, csr, done, W1, b1, W2, hsA);
  kB<<<250, 1024, 0, stream>>>(hsA, cnt, csr, b2, W3, hsB);
  kC<<<250, 1024, 0, stream>>>(hsB, cnt, csr, b3, Wd1, partial, done,
                               bd1, Wd2, bd2, Wd3, bd3, Wd4, bd4, out);
}